// Round 8
// baseline (428.910 us; speedup 1.0000x reference)
//
#include <hip/hip_runtime.h>

#define BB 64
#define SS 512
#define HH 768
#define HH4 (HH / 4)      // 192 float4 per row
#define NBD 5
#define NC 9
#define NR 4096
#define NB_BD 2048        // boundary blocks
#define NB_RG 1024        // region blocks (4 regions each)
#define NBLK (NB_BD + NB_RG)   // 3072

// ---------------------------------------------------------------------------
// Fused kernel. Block-uniform role split: bid%3==0 -> region block (1024,
// one wave per region, straight-line clamped loads, no LDS); else -> bd
// block (2048, 4 waves x 4 consecutive tokens, Ws register-resident).
// Interleave overlaps region's latency-bound reads with bd's HBM stream;
// region re-reads are L2/L3-absorbed (R2 evidence: FETCH == 100 MB).
// Finalization is folded in via last-block threadfence reduction.
// ---------------------------------------------------------------------------
__global__ __launch_bounds__(256) void fused_kernel(
    const float* __restrict__ wr, const float* __restrict__ Ws,
    const float* __restrict__ bs, const int* __restrict__ tgt,
    const int* __restrict__ seg,
    const float* __restrict__ Wr, const float* __restrict__ br,
    const int* __restrict__ rstart, const int* __restrict__ rlen,
    const int* __restrict__ rbatch, const int* __restrict__ rlabel,
    float2* __restrict__ bd_part, float* __restrict__ rnll,
    unsigned int* __restrict__ counter, float* __restrict__ out)
{
    const int tid  = threadIdx.x;
    const int wid  = tid >> 6;
    const int lane = tid & 63;
    const int bid  = blockIdx.x;

    if (bid % 3 != 0) {
        // ======================= boundary path =======================
        const int bb = bid - bid / 3 - 1;   // 0..2047
        const int gw = bb * 4 + wid;        // 0..8191, tokens [4gw,4gw+4)

        // Ws fragment register-resident: h = 4*lane + 256*j + e (contig f4)
        float wreg[3][4][NBD];
        #pragma unroll
        for (int j = 0; j < 3; ++j) {
            const float4* wp = (const float4*)(Ws + (4 * lane + 256 * j) * NBD);
            #pragma unroll
            for (int p = 0; p < 5; ++p) {
                const float4 f = wp[p];
                const float vv[4] = {f.x, f.y, f.z, f.w};
                #pragma unroll
                for (int q = 0; q < 4; ++q) {
                    const int flat = 4 * p + q;            // 0..19
                    wreg[j][flat / NBD][flat % NBD] = vv[q];
                }
            }
        }
        const float b0 = bs[0], b1 = bs[1], b2 = bs[2], b3 = bs[3], b4 = bs[4];

        // all 12 row-float4s preloaded (independent -> deep MLP)
        const float4* base = (const float4*)wr + (size_t)(4 * gw) * HH4;
        float4 v[4][3];
        #pragma unroll
        for (int i = 0; i < 4; ++i)
            #pragma unroll
            for (int j = 0; j < 3; ++j)
                v[i][j] = base[i * HH4 + lane + 64 * j];

        float nll_sum = 0.f, msk_sum = 0.f;

        #pragma unroll
        for (int i = 0; i < 4; ++i) {
            float dot[NBD] = {0.f, 0.f, 0.f, 0.f, 0.f};
            #pragma unroll
            for (int j = 0; j < 3; ++j) {
                const float x[4] = {v[i][j].x, v[i][j].y, v[i][j].z, v[i][j].w};
                #pragma unroll
                for (int e = 0; e < 4; ++e)
                    #pragma unroll
                    for (int k = 0; k < NBD; ++k)
                        dot[k] += x[e] * wreg[j][e][k];
            }

            #pragma unroll
            for (int k = 0; k < NBD; ++k)
                #pragma unroll
                for (int off = 32; off; off >>= 1)
                    dot[k] += __shfl_xor(dot[k], off);

            if (lane == 0) {
                const int token = 4 * gw + i;
                float l[NBD] = {dot[0] + b0, dot[1] + b1, dot[2] + b2,
                                dot[3] + b3, dot[4] + b4};
                float m = l[0];
                #pragma unroll
                for (int k = 1; k < NBD; ++k) m = fmaxf(m, l[k]);
                float ssum = 0.f;
                #pragma unroll
                for (int k = 0; k < NBD; ++k) ssum += expf(l[k] - m);
                const float lse = logf(ssum);
                const int   t   = tgt[token];
                const float msk = (float)seg[token];
                nll_sum += msk * (-(l[t] - m - lse));
                msk_sum += msk;
            }
        }

        __shared__ float s_n[4], s_m[4];
        if (lane == 0) { s_n[wid] = nll_sum; s_m[wid] = msk_sum; }
        __syncthreads();
        if (tid == 0) {
            bd_part[bb] = make_float2(s_n[0] + s_n[1] + s_n[2] + s_n[3],
                                      s_m[0] + s_m[1] + s_m[2] + s_m[3]);
        }
    } else {
        // ======================= region path =======================
        const int r = (bid / 3) * 4 + wid;   // 0..4095

        const int   start = rstart[r];
        const int   len   = rlen[r] + 1;     // 1..16 rows
        const int   b     = rbatch[r];
        const float inv   = 1.0f / (float)len;

        const float4* base =
            (const float4*)wr + ((size_t)b * SS + start) * HH4;

        float4 m0 = {0.f, 0.f, 0.f, 0.f};
        float4 m1 = {0.f, 0.f, 0.f, 0.f};
        float4 m2 = {0.f, 0.f, 0.f, 0.f};

        #pragma unroll
        for (int row = 0; row < 16; ++row) {
            const int rc = (row < len) ? row : (len - 1);  // always-valid addr
            const float4 u0 = base[(size_t)rc * HH4 + lane];
            const float4 u1 = base[(size_t)rc * HH4 + lane + 64];
            const float4 u2 = base[(size_t)rc * HH4 + lane + 128];
            const float  w  = (row < len) ? inv : 0.f;     // wave-uniform SGPR
            m0.x += w * u0.x; m0.y += w * u0.y; m0.z += w * u0.z; m0.w += w * u0.w;
            m1.x += w * u1.x; m1.y += w * u1.y; m1.z += w * u1.z; m1.w += w * u1.w;
            m2.x += w * u2.x; m2.y += w * u2.y; m2.z += w * u2.z; m2.w += w * u2.w;
        }

        float part[NC];
        #pragma unroll
        for (int c = 0; c < NC; ++c) part[c] = 0.f;

        const float mv[3][4] = {{m0.x, m0.y, m0.z, m0.w},
                                {m1.x, m1.y, m1.z, m1.w},
                                {m2.x, m2.y, m2.z, m2.w}};
        #pragma unroll
        for (int g = 0; g < 3; ++g) {
            const int f = lane + 64 * g;
            const float4* wv = (const float4*)(Wr + (size_t)4 * f * NC);
            #pragma unroll
            for (int j = 0; j < 9; ++j) {
                const float4 x = wv[j];
                const float vv[4] = {x.x, x.y, x.z, x.w};
                #pragma unroll
                for (int q = 0; q < 4; ++q) {
                    const int flat = 4 * j + q;            // 0..35 = e*9+c
                    part[flat % NC] += mv[g][flat / NC] * vv[q];
                }
            }
        }

        #pragma unroll
        for (int c = 0; c < NC; ++c)
            #pragma unroll
            for (int off = 32; off; off >>= 1)
                part[c] += __shfl_xor(part[c], off);

        if (lane == 0) {
            float l[NC];
            #pragma unroll
            for (int c = 0; c < NC; ++c) l[c] = part[c] + br[c];
            float mx = l[0];
            #pragma unroll
            for (int c = 1; c < NC; ++c) mx = fmaxf(mx, l[c]);
            float ssum = 0.f;
            #pragma unroll
            for (int c = 0; c < NC; ++c) ssum += expf(l[c] - mx);
            const float lse = logf(ssum);
            const int   t   = rlabel[r];
            rnll[r] = -(l[t] - mx - lse);
        }
    }

    // ================= last-block finalization =================
    __syncthreads();                       // all this block's stores issued
    __shared__ bool s_last;
    if (tid == 0) {
        __threadfence();                   // release: publish block's stores
        const unsigned int old = atomicAdd(counter, 1u);
        s_last = (old == (unsigned int)(NBLK - 1));
        __threadfence();                   // acquire side for the last block
    }
    __syncthreads();                       // broadcast s_last (hb chain)
    if (!s_last) return;                   // block-uniform exit

    double a = 0.0, c = 0.0, e = 0.0;
    for (int i = tid; i < NB_BD; i += 256) {
        const float2 p = bd_part[i];
        a += (double)p.x;
        c += (double)p.y;
    }
    for (int i = tid; i < NR; i += 256) e += (double)rnll[i];

    #pragma unroll
    for (int off = 32; off; off >>= 1) {
        a += __shfl_xor(a, off);
        c += __shfl_xor(c, off);
        e += __shfl_xor(e, off);
    }

    __shared__ double sa[4], sc[4], se[4];
    if (lane == 0) { sa[wid] = a; sc[wid] = c; se[wid] = e; }
    __syncthreads();

    if (tid == 0) {
        const double A = sa[0] + sa[1] + sa[2] + sa[3];
        const double C = sc[0] + sc[1] + sc[2] + sc[3];
        const double E = se[0] + se[1] + se[2] + se[3];
        const float ent = (float)(E / (double)NR);
        const float bd  = (float)(A / (C + 1e-6));
        out[0] = 0.3f * ent + 0.7f * bd;
    }
}

extern "C" void kernel_launch(void* const* d_in, const int* in_sizes, int n_in,
                              void* d_out, int out_size, void* d_ws, size_t ws_size,
                              hipStream_t stream)
{
    const float* wr     = (const float*)d_in[0];
    const float* Ws     = (const float*)d_in[1];
    const float* bs     = (const float*)d_in[2];
    const float* Wr     = (const float*)d_in[3];
    const float* br     = (const float*)d_in[4];
    const int*   tgt    = (const int*)d_in[5];
    const int*   seg    = (const int*)d_in[6];
    const int*   rstart = (const int*)d_in[7];
    const int*   rlen   = (const int*)d_in[8];
    const int*   rbatch = (const int*)d_in[9];
    const int*   rlabel = (const int*)d_in[10];

    float2*       bdp  = (float2*)d_ws;                                // 16 KB
    float*        rnll = (float*)((char*)d_ws + NB_BD * sizeof(float2)); // 16 KB
    unsigned int* ctr  = (unsigned int*)((char*)d_ws + NB_BD * sizeof(float2)
                                         + NR * sizeof(float));

    hipMemsetAsync(ctr, 0, sizeof(unsigned int), stream);
    fused_kernel<<<NBLK, 256, 0, stream>>>(wr, Ws, bs, tgt, seg,
                                           Wr, br, rstart, rlen, rbatch, rlabel,
                                           bdp, rnll, ctr, (float*)d_out);
}

// Round 11
// 190.907 us; speedup vs baseline: 2.2467x; 2.2467x over previous
//
#include <hip/hip_runtime.h>

#define BB 64
#define SS 512
#define HH 768
#define HH4 (HH / 4)      // 192 float4 per row
#define NBD 5
#define NC 9
#define NR 4096
#define NB_BD 2048        // boundary blocks (bid%3 != 0)
#define NB_RG 1024        // region blocks (bid%3 == 0), 4 regions each
#define NBLK (NB_BD + NB_RG)   // 3072

// ---------------------------------------------------------------------------
// Fused kernel, R2-derived (R2 measured 59.5us, VGPR 48). Single change vs
// R2: region path is per-WAVE with an exact-len loop -- no LDS, no barriers,
// no clamped over-read (halves region L2 traffic) -- and region blocks drop
// 4096 -> 1024 so bd:region resident ratio is 2:1. bd path is VERBATIM R2
// (v[3] loaded per token inside the loop; that kept VGPR at 48 -- R8 showed
// preloading v[4][3] pushes VGPR to 100 and occupancy to 18%).
// ---------------------------------------------------------------------------
__global__ __launch_bounds__(256) void fused_kernel(
    const float* __restrict__ wr, const float* __restrict__ Ws,
    const float* __restrict__ bs, const int* __restrict__ tgt,
    const int* __restrict__ seg,
    const float* __restrict__ Wr, const float* __restrict__ br,
    const int* __restrict__ rstart, const int* __restrict__ rlen,
    const int* __restrict__ rbatch, const int* __restrict__ rlabel,
    float2* __restrict__ bd_part, float* __restrict__ rnll)
{
    const int tid  = threadIdx.x;
    const int wid  = tid >> 6;
    const int lane = tid & 63;
    const int bid  = blockIdx.x;

    if (bid % 3 != 0) {
        // ======================= boundary path (verbatim R2) =============
        const int bb = bid - bid / 3 - 1;   // 0..2047
        const int gw = bb * 4 + wid;        // 0..8191

        float wreg[3][4][NBD];
        #pragma unroll
        for (int j = 0; j < 3; ++j) {
            const float4* wp = (const float4*)(Ws + (4 * lane + 256 * j) * NBD);
            #pragma unroll
            for (int p = 0; p < 5; ++p) {
                const float4 f = wp[p];
                const float vv[4] = {f.x, f.y, f.z, f.w};
                #pragma unroll
                for (int q = 0; q < 4; ++q) {
                    const int flat = 4 * p + q;            // 0..19
                    wreg[j][flat / NBD][flat % NBD] = vv[q];
                }
            }
        }
        const float b0 = bs[0], b1 = bs[1], b2 = bs[2], b3 = bs[3], b4 = bs[4];

        float nll_sum = 0.f, msk_sum = 0.f;

        #pragma unroll
        for (int i = 0; i < 4; ++i) {
            const int token = gw + 8192 * i;
            const float4* row4 = (const float4*)(wr + (size_t)token * HH);

            float4 v[3];
            #pragma unroll
            for (int j = 0; j < 3; ++j) v[j] = row4[lane + 64 * j];

            float dot[NBD] = {0.f, 0.f, 0.f, 0.f, 0.f};
            #pragma unroll
            for (int j = 0; j < 3; ++j) {
                const float x[4] = {v[j].x, v[j].y, v[j].z, v[j].w};
                #pragma unroll
                for (int e = 0; e < 4; ++e)
                    #pragma unroll
                    for (int k = 0; k < NBD; ++k)
                        dot[k] += x[e] * wreg[j][e][k];
            }

            #pragma unroll
            for (int k = 0; k < NBD; ++k)
                #pragma unroll
                for (int off = 32; off; off >>= 1)
                    dot[k] += __shfl_xor(dot[k], off);

            if (lane == 0) {
                float l[NBD] = {dot[0] + b0, dot[1] + b1, dot[2] + b2,
                                dot[3] + b3, dot[4] + b4};
                float m = l[0];
                #pragma unroll
                for (int k = 1; k < NBD; ++k) m = fmaxf(m, l[k]);
                float ssum = 0.f;
                #pragma unroll
                for (int k = 0; k < NBD; ++k) ssum += expf(l[k] - m);
                const float lse = logf(ssum);
                const int   t   = tgt[token];
                const float msk = (float)seg[token];
                nll_sum += msk * (-(l[t] - m - lse));
                msk_sum += msk;
            }
        }

        __shared__ float s_n[4], s_m[4];
        if (lane == 0) { s_n[wid] = nll_sum; s_m[wid] = msk_sum; }
        __syncthreads();
        if (tid == 0) {
            bd_part[bb] = make_float2(s_n[0] + s_n[1] + s_n[2] + s_n[3],
                                      s_m[0] + s_m[1] + s_m[2] + s_m[3]);
        }
    } else {
        // ============ region path: one wave per region, exact len ========
        const int r = (bid / 3) * 4 + wid;   // 0..4095

        const int   start = rstart[r];
        const int   len   = rlen[r] + 1;     // 1..16 rows
        const int   b     = rbatch[r];
        const float inv   = 1.0f / (float)len;

        const float4* base =
            (const float4*)wr + ((size_t)b * SS + start) * HH4;

        float4 m0 = {0.f, 0.f, 0.f, 0.f};
        float4 m1 = {0.f, 0.f, 0.f, 0.f};
        float4 m2 = {0.f, 0.f, 0.f, 0.f};

        #pragma unroll 2
        for (int row = 0; row < len; ++row) {
            const float4* p = base + (size_t)row * HH4;
            const float4 u0 = p[lane];
            const float4 u1 = p[lane + 64];
            const float4 u2 = p[lane + 128];
            m0.x += u0.x; m0.y += u0.y; m0.z += u0.z; m0.w += u0.w;
            m1.x += u1.x; m1.y += u1.y; m1.z += u1.z; m1.w += u1.w;
            m2.x += u2.x; m2.y += u2.y; m2.z += u2.z; m2.w += u2.w;
        }

        float part[NC];
        #pragma unroll
        for (int c = 0; c < NC; ++c) part[c] = 0.f;

        const float mv[3][4] = {{m0.x * inv, m0.y * inv, m0.z * inv, m0.w * inv},
                                {m1.x * inv, m1.y * inv, m1.z * inv, m1.w * inv},
                                {m2.x * inv, m2.y * inv, m2.z * inv, m2.w * inv}};
        #pragma unroll
        for (int g = 0; g < 3; ++g) {
            const int f = lane + 64 * g;
            const float4* wv = (const float4*)(Wr + (size_t)4 * f * NC);
            #pragma unroll
            for (int j = 0; j < 9; ++j) {
                const float4 x = wv[j];
                const float vv[4] = {x.x, x.y, x.z, x.w};
                #pragma unroll
                for (int q = 0; q < 4; ++q) {
                    const int flat = 4 * j + q;            // 0..35 = e*9+c
                    part[flat % NC] += mv[g][flat / NC] * vv[q];
                }
            }
        }

        #pragma unroll
        for (int c = 0; c < NC; ++c)
            #pragma unroll
            for (int off = 32; off; off >>= 1)
                part[c] += __shfl_xor(part[c], off);

        if (lane == 0) {
            float l[NC];
            #pragma unroll
            for (int c = 0; c < NC; ++c) l[c] = part[c] + br[c];
            float mx = l[0];
            #pragma unroll
            for (int c = 1; c < NC; ++c) mx = fmaxf(mx, l[c]);
            float ssum = 0.f;
            #pragma unroll
            for (int c = 0; c < NC; ++c) ssum += expf(l[c] - mx);
            const float lse = logf(ssum);
            const int   t   = rlabel[r];
            rnll[r] = -(l[t] - mx - lse);
        }
    }
}

// ---------------------------------------------------------------------------
// Final reduction (1 block, 256 threads, f64 accumulation). ~4us measured.
// ---------------------------------------------------------------------------
__global__ __launch_bounds__(256) void fin_kernel(
    const float2* __restrict__ bdp, const float* __restrict__ rnll,
    float* __restrict__ out)
{
    const int tid  = threadIdx.x;
    const int wid  = tid >> 6;
    const int lane = tid & 63;

    double a = 0.0, c = 0.0, e = 0.0;
    for (int i = tid; i < NB_BD; i += 256) {
        const float2 p = bdp[i];
        a += (double)p.x;
        c += (double)p.y;
    }
    for (int i = tid; i < NR; i += 256) e += (double)rnll[i];

    #pragma unroll
    for (int off = 32; off; off >>= 1) {
        a += __shfl_xor(a, off);
        c += __shfl_xor(c, off);
        e += __shfl_xor(e, off);
    }

    __shared__ double sa[4], sc[4], se[4];
    if (lane == 0) { sa[wid] = a; sc[wid] = c; se[wid] = e; }
    __syncthreads();

    if (tid == 0) {
        const double A = sa[0] + sa[1] + sa[2] + sa[3];
        const double C = sc[0] + sc[1] + sc[2] + sc[3];
        const double E = se[0] + se[1] + se[2] + se[3];
        const float ent = (float)(E / (double)NR);
        const float bd  = (float)(A / (C + 1e-6));
        out[0] = 0.3f * ent + 0.7f * bd;
    }
}

extern "C" void kernel_launch(void* const* d_in, const int* in_sizes, int n_in,
                              void* d_out, int out_size, void* d_ws, size_t ws_size,
                              hipStream_t stream)
{
    const float* wr     = (const float*)d_in[0];
    const float* Ws     = (const float*)d_in[1];
    const float* bs     = (const float*)d_in[2];
    const float* Wr     = (const float*)d_in[3];
    const float* br     = (const float*)d_in[4];
    const int*   tgt    = (const int*)d_in[5];
    const int*   seg    = (const int*)d_in[6];
    const int*   rstart = (const int*)d_in[7];
    const int*   rlen   = (const int*)d_in[8];
    const int*   rbatch = (const int*)d_in[9];
    const int*   rlabel = (const int*)d_in[10];

    float2* bdp  = (float2*)d_ws;                                   // 16 KB
    float*  rnll = (float*)((char*)d_ws + NB_BD * sizeof(float2));  // 16 KB

    fused_kernel<<<NBLK, 256, 0, stream>>>(wr, Ws, bs, tgt, seg,
                                           Wr, br, rstart, rlen, rbatch, rlabel,
                                           bdp, rnll);
    fin_kernel<<<1, 256, 0, stream>>>(bdp, rnll, (float*)d_out);
}